// Round 3
// baseline (485.017 us; speedup 1.0000x reference)
//
#include <hip/hip_runtime.h>
#include <hip/hip_bf16.h>

#define NPATCH 29791   // 31*31*31 patches
#define WPB 4          // waves per block
#define PPW 8          // patches per wave
#define GRID_P 931     // ceil(29791 / 32)

typedef short short8 __attribute__((ext_vector_type(8)));   // 8 bf16 raw bits
typedef float f32x4  __attribute__((ext_vector_type(4)));

__device__ __forceinline__ unsigned short bfbits(float f) {
    __hip_bfloat16 h = __float2bfloat16(f);
    return *reinterpret_cast<unsigned short*>(&h);
}

// ============================ patch kernel =============================
// 4 waves/block, 1 patch per wave per iteration, 8 iterations.
// LDS (static, 41,472 B, phase-overlaid):
//   phase 1: bf16 weights [tap 28][c 32][ci 16]  (28,672 B; tap 27 = zeros)
//   phase 2: 4 slabs of 10,368 B: patch halo [6][6][6] voxels * 48 B (24 ci slots)
__global__ __launch_bounds__(256, 2) void patch_kernel(
    const float* __restrict__ x,
    const float* __restrict__ cw,
    const float* __restrict__ bg,
    const float* __restrict__ bb,
    const float* __restrict__ bm,
    const float* __restrict__ bv,
    const float* __restrict__ w1,   // se_w1 [4][32]
    const float* __restrict__ w2,   // se_w2 [32][4]
    float* __restrict__ out)
{
    __shared__ __align__(16) char lds[41472];

    const int tid  = threadIdx.x;
    const int wid  = tid >> 6;
    const int lane = tid & 63;

    // ---------- phase 1: stage BN-folded bf16 weights into LDS ----------
    // thread handles (tap,c) pairs p = c + 32*tap, writes 16 ci contiguously (32 B)
    unsigned short* wsh = reinterpret_cast<unsigned short*>(lds);
    for (int p = tid; p < 864; p += 256) {          // 864 = 27*32
        const int c   = p & 31;
        const int tap = p >> 5;
        const float inv = bg[c] * rsqrtf(bv[c] + 1e-5f);
        unsigned int u[8];
#pragma unroll
        for (int j = 0; j < 8; ++j) {
            const float v0 = cw[c * 432 + (2 * j)     * 27 + tap] * inv;
            const float v1 = cw[c * 432 + (2 * j + 1) * 27 + tap] * inv;
            u[j] = (unsigned int)bfbits(v0) | ((unsigned int)bfbits(v1) << 16);
        }
        uint4* dst = reinterpret_cast<uint4*>(lds + tap * 1024 + c * 32);
        dst[0] = make_uint4(u[0], u[1], u[2], u[3]);
        dst[1] = make_uint4(u[4], u[5], u[6], u[7]);
    }
    // zero plane for tap 27 (bytes [27648, 28672))
    reinterpret_cast<unsigned int*>(lds + 27648)[tid] = 0u;
    __syncthreads();

    // ---------- B fragments -> registers (weights become dead in LDS) ----------
    const int g  = lane >> 4;        // k-group of this lane
    const int g1 = g >> 1;           // tap parity within a K=32 step
    const int ge = g & 1;            // ci half (0..7 / 8..15)
    const int c0 = lane & 15;        // B column / A row / C column

    short8 bfr0[14], bfr1[14];
    {
        const char* bbase = lds + c0 * 32 + ge * 16 + g1 * 1024;
#pragma unroll
        for (int s = 0; s < 14; ++s) {
            bfr0[s] = *reinterpret_cast<const short8*>(bbase + s * 2048);        // ch 0..15
            bfr1[s] = *reinterpret_cast<const short8*>(bbase + s * 2048 + 512);  // ch 16..31
        }
    }
    __syncthreads();   // all B-reads done before slab phase overwrites LDS

    // per-lane constants
    const float inv0  = bg[c0]      * rsqrtf(bv[c0]      + 1e-5f);
    const float inv1  = bg[c0 + 16] * rsqrtf(bv[c0 + 16] + 1e-5f);
    const float bias0 = bb[c0]      - bm[c0]      * inv0;
    const float bias1 = bb[c0 + 16] - bm[c0 + 16] * inv1;
    const float4 wv0 = *reinterpret_cast<const float4*>(w2 + c0 * 4);
    const float4 wv1 = *reinterpret_cast<const float4*>(w2 + (c0 + 16) * 4);
    const int jj = lane & 31;
    const float w1v0 = w1[jj], w1v1 = w1[32 + jj], w1v2 = w1[64 + jj], w1v3 = w1[96 + jj];

    // ---------- phase 2: per-wave slab ----------
    char* slab = lds + wid * 10368;
    {   // zero whole slab once (halo = per-patch conv zero-padding)
        uint4 z = make_uint4(0u, 0u, 0u, 0u);
        uint4* sp = reinterpret_cast<uint4*>(slab);
        for (int i = lane; i < 648; i += 64) sp[i] = z;
    }

    // fill-position and A-fragment addressing (lane-constant across iters)
    const int fd = lane >> 4, fh = (lane >> 2) & 3, fw = lane & 3;
    const float* xg0 = x + fd * 4096 + fh * 64 + fw;
    char* sv = slab + ((fd + 1) * 36 + (fh + 1) * 6 + (fw + 1)) * 48;
    const char* abase = slab + ((c0 >> 2) * 6 + (c0 & 3)) * 48 + ge * 16;

    const int pid0 = blockIdx.x * (WPB * PPW) + wid;
    for (int it = 0; it < PPW; ++it) {
        const int pid = pid0 + it * WPB;
        if (pid >= NPATCH) break;
        const int pz   = pid / 961;
        const int prem = pid - pz * 961;
        const int py   = prem / 31;
        const int px   = prem - py * 31;

        // WAR guard: previous iteration's LDS reads fully retired
        asm volatile("s_waitcnt lgkmcnt(0)" ::: "memory");
        __builtin_amdgcn_sched_barrier(0);

        // fill interior 4x4x4 voxels x 16 ci (f32 -> packed bf16x2)
        const float* xg = xg0 + (2 * pz) * 4096 + (2 * py) * 64 + (2 * px);
#pragma unroll
        for (int ci = 0; ci < 16; ci += 2) {
            const float v0 = xg[ci * 262144];
            const float v1 = xg[(ci + 1) * 262144];
            const unsigned int u = (unsigned int)bfbits(v0) | ((unsigned int)bfbits(v1) << 16);
            *reinterpret_cast<unsigned int*>(sv + ci * 2) = u;
        }
        // make fill visible to all lanes of this wave before fragment reads
        asm volatile("s_waitcnt lgkmcnt(0)" ::: "memory");
        __builtin_amdgcn_sched_barrier(0);

        // ---- GEMM: M=64 pos x N=32 ch x K=448 (k = tap*16 + ci, tap 27 zero) ----
        f32x4 acc[4][2];
#pragma unroll
        for (int mm = 0; mm < 4; ++mm)
#pragma unroll
            for (int nn = 0; nn < 2; ++nn)
                acc[mm][nn] = (f32x4){0.f, 0.f, 0.f, 0.f};

#pragma unroll
        for (int s = 0; s < 14; ++s) {
            const int t0 = 2 * s, t1 = 2 * s + 1;
            const int D0 = ((t0 / 9) * 36 + ((t0 % 9) / 3) * 6 + (t0 % 3)) * 48;
            const int D1 = (t1 < 27) ? (((t1 / 9) * 36 + ((t1 % 9) / 3) * 6 + (t1 % 3)) * 48) : 0;
            const char* ap = abase + (g1 ? D1 : D0);
            short8 a0 = *reinterpret_cast<const short8*>(ap);
            short8 a1 = *reinterpret_cast<const short8*>(ap + 1728);
            short8 a2 = *reinterpret_cast<const short8*>(ap + 3456);
            short8 a3 = *reinterpret_cast<const short8*>(ap + 5184);
            acc[0][0] = __builtin_amdgcn_mfma_f32_16x16x32_bf16(a0, bfr0[s], acc[0][0], 0, 0, 0);
            acc[0][1] = __builtin_amdgcn_mfma_f32_16x16x32_bf16(a0, bfr1[s], acc[0][1], 0, 0, 0);
            acc[1][0] = __builtin_amdgcn_mfma_f32_16x16x32_bf16(a1, bfr0[s], acc[1][0], 0, 0, 0);
            acc[1][1] = __builtin_amdgcn_mfma_f32_16x16x32_bf16(a1, bfr1[s], acc[1][1], 0, 0, 0);
            acc[2][0] = __builtin_amdgcn_mfma_f32_16x16x32_bf16(a2, bfr0[s], acc[2][0], 0, 0, 0);
            acc[2][1] = __builtin_amdgcn_mfma_f32_16x16x32_bf16(a2, bfr1[s], acc[2][1], 0, 0, 0);
            acc[3][0] = __builtin_amdgcn_mfma_f32_16x16x32_bf16(a3, bfr0[s], acc[3][0], 0, 0, 0);
            acc[3][1] = __builtin_amdgcn_mfma_f32_16x16x32_bf16(a3, bfr1[s], acc[3][1], 0, 0, 0);
        }

        // ---- epilogue: bias+ReLU; C/D: col=lane&15, row=(lane>>4)*4+reg ----
        // pos = mm*16 + g*4 + j  ->  d=mm, h=g, w=j
        float yv0[4][4], yv1[4][4];
#pragma unroll
        for (int mm = 0; mm < 4; ++mm)
#pragma unroll
            for (int j = 0; j < 4; ++j) {
                yv0[mm][j] = fmaxf(acc[mm][0][j] + bias0, 0.f);
                yv1[mm][j] = fmaxf(acc[mm][1][j] + bias1, 0.f);
            }

        // desc: mean over 64 positions per channel
        float p0 = 0.f, p1 = 0.f;
#pragma unroll
        for (int mm = 0; mm < 4; ++mm)
#pragma unroll
            for (int j = 0; j < 4; ++j) { p0 += yv0[mm][j]; p1 += yv1[mm][j]; }
        p0 += __shfl_xor(p0, 16); p0 += __shfl_xor(p0, 32);
        p1 += __shfl_xor(p1, 16); p1 += __shfl_xor(p1, 32);
        const float desc0 = p0 * (1.f / 64.f);
        const float desc1 = p1 * (1.f / 64.f);

        // SE (each 32-lane half holds the full 32-ch descriptor)
        const float dj = (lane & 16) ? desc1 : desc0;
        float z0 = dj * w1v0, z1 = dj * w1v1, z2 = dj * w1v2, z3 = dj * w1v3;
#pragma unroll
        for (int msk = 1; msk <= 16; msk <<= 1) {
            z0 += __shfl_xor(z0, msk);
            z1 += __shfl_xor(z1, msk);
            z2 += __shfl_xor(z2, msk);
            z3 += __shfl_xor(z3, msk);
        }
        z0 = fmaxf(z0, 0.f); z1 = fmaxf(z1, 0.f); z2 = fmaxf(z2, 0.f); z3 = fmaxf(z3, 0.f);
        const float s0 = z0 * wv0.x + z1 * wv0.y + z2 * wv0.z + z3 * wv0.w;
        const float s1 = z0 * wv1.x + z1 * wv1.y + z2 * wv1.z + z3 * wv1.w;
        const float attn0 = 0.125f / (1.f + __expf(-s0));   // 1/8 pool mean folded in
        const float attn1 = 0.125f / (1.f + __expf(-s1));

        // ---- 2x2x2 pool + fold (pre-divided by analytic coverage) ----
        const int ph = g >> 1;
        const bool writer = (g & 1) == 0;    // g in {0,2} carry h-pair sums
#pragma unroll
        for (int mp = 0; mp < 2; ++mp)
#pragma unroll
            for (int jp = 0; jp < 2; ++jp) {
                float t0s = yv0[2 * mp][2 * jp] + yv0[2 * mp][2 * jp + 1] +
                            yv0[2 * mp + 1][2 * jp] + yv0[2 * mp + 1][2 * jp + 1];
                float t1s = yv1[2 * mp][2 * jp] + yv1[2 * mp][2 * jp + 1] +
                            yv1[2 * mp + 1][2 * jp] + yv1[2 * mp + 1][2 * jp + 1];
                t0s += __shfl_xor(t0s, 16);
                t1s += __shfl_xor(t1s, 16);
                if (writer) {
                    const int td = pz + mp, th = py + ph, tw = px + jp;
                    const float cd  = (td == 0 || td == 31) ? 1.f : 2.f;
                    const float chh = (th == 0 || th == 31) ? 1.f : 2.f;
                    const float cww = (tw == 0 || tw == 31) ? 1.f : 2.f;
                    const float rw = 1.f / (cd * chh * cww);
                    const int base = td * 1024 + th * 32 + tw;
                    atomicAdd(out + c0 * 32768 + base,        t0s * attn0 * rw);
                    atomicAdd(out + (c0 + 16) * 32768 + base, t1s * attn1 * rw);
                }
            }
    }
}

// ---------------- residual: out += bn(conv1x1 stride-2) ----------------
__global__ void res_kernel(const float* __restrict__ x,
                           const float* __restrict__ dw,
                           const float* __restrict__ dg,
                           const float* __restrict__ dbb,
                           const float* __restrict__ dm,
                           const float* __restrict__ dv,
                           float* __restrict__ out)
{
    const int t = blockIdx.x * 256 + threadIdx.x;     // 1,048,576 threads
    const int c = t >> 15;
    const int v = t & 32767;
    const int d = v >> 10, h = (v >> 5) & 31, w = v & 31;
    const float* xp = x + ((2 * d) * 4096 + (2 * h) * 64 + (2 * w));
    float acc = 0.f;
#pragma unroll
    for (int ci = 0; ci < 16; ++ci)
        acc = fmaf(xp[ci * 262144], dw[c * 16 + ci], acc);
    const float inv = dg[c] * rsqrtf(dv[c] + 1e-5f);
    out[t] += acc * inv + (dbb[c] - dm[c] * inv);
}

extern "C" void kernel_launch(void* const* d_in, const int* in_sizes, int n_in,
                              void* d_out, int out_size, void* d_ws, size_t ws_size,
                              hipStream_t stream)
{
    const float* x      = (const float*)d_in[0];
    const float* conv_w = (const float*)d_in[1];
    const float* bn_g   = (const float*)d_in[2];
    const float* bn_b   = (const float*)d_in[3];
    const float* bn_m   = (const float*)d_in[4];
    const float* bn_v   = (const float*)d_in[5];
    const float* se_w1  = (const float*)d_in[6];
    const float* se_w2  = (const float*)d_in[7];
    const float* down_w = (const float*)d_in[8];
    const float* dbn_g  = (const float*)d_in[9];
    const float* dbn_b  = (const float*)d_in[10];
    const float* dbn_m  = (const float*)d_in[11];
    const float* dbn_v  = (const float*)d_in[12];

    float* out = (float*)d_out;

    hipMemsetAsync(d_out, 0, (size_t)out_size * sizeof(float), stream);

    patch_kernel<<<GRID_P, 256, 0, stream>>>(
        x, conv_w, bn_g, bn_b, bn_m, bn_v, se_w1, se_w2, out);

    res_kernel<<<4096, 256, 0, stream>>>(x, down_w, dbn_g, dbn_b, dbn_m, dbn_v, out);
}

// Round 5
// 325.698 us; speedup vs baseline: 1.4892x; 1.4892x over previous
//
#include <hip/hip_runtime.h>
#include <hip/hip_bf16.h>

typedef short short8 __attribute__((ext_vector_type(8)));   // 8 bf16 raw bits
typedef float f32x4  __attribute__((ext_vector_type(4)));

__device__ __forceinline__ unsigned short bfbits(float f) {
    __hip_bfloat16 h = __float2bfloat16(f);
    return *reinterpret_cast<unsigned short*>(&h);
}
__device__ __forceinline__ unsigned int pack2(float a, float b) {
    return (unsigned int)bfbits(a) | ((unsigned int)bfbits(b) << 16);
}

// ============================ patch kernel =============================
// Grid 964 = 241 column-groups x 4 pz-ranges. Block = 4 waves; wave w handles
// column c = cg*4+w (c = py*31+px), patches pz = rg*8 .. rg*8+npz-1.
// LDS (static 41,472 B, phase-overlaid):
//   phase 1: bf16 BN-folded weights [tap 28][c 32][ci 16] (28,672 B)
//   phase 2: 4 slabs x 10,368 B: halo [6][6][6] voxels x 48 B (24 bf16 slots)
__global__ __launch_bounds__(256, 2) void patch_kernel(
    const float* __restrict__ x,
    const float* __restrict__ cw,
    const float* __restrict__ bg,
    const float* __restrict__ bb,
    const float* __restrict__ bm,
    const float* __restrict__ bv,
    const float* __restrict__ w1,   // se_w1 [4][32]
    const float* __restrict__ w2,   // se_w2 [32][4]
    float* __restrict__ out)
{
    __shared__ __align__(16) char lds[41472];

    const int tid  = threadIdx.x;
    const int wid  = tid >> 6;
    const int lane = tid & 63;

    // bijective XCD swizzle of 964 blocks (q=120, r=4)
    const int bi  = blockIdx.x;
    const int xcd = bi & 7, sidx = bi >> 3;
    const int wg  = (xcd < 4 ? xcd * 121 : 484 + (xcd - 4) * 120) + sidx;
    const int cg  = wg % 241;
    const int rg  = wg / 241;

    // ---------- phase 1: stage BN-folded bf16 weights into LDS ----------
    for (int p = tid; p < 864; p += 256) {          // 864 = 27*32 (tap,c)
        const int c   = p & 31;
        const int tap = p >> 5;
        const float inv = bg[c] * rsqrtf(bv[c] + 1e-5f);
        unsigned int uu[8];
#pragma unroll
        for (int j = 0; j < 8; ++j) {
            const float v0 = cw[c * 432 + (2 * j)     * 27 + tap] * inv;
            const float v1 = cw[c * 432 + (2 * j + 1) * 27 + tap] * inv;
            uu[j] = pack2(v0, v1);
        }
        uint4* dst = reinterpret_cast<uint4*>(lds + tap * 1024 + c * 32);
        dst[0] = make_uint4(uu[0], uu[1], uu[2], uu[3]);
        dst[1] = make_uint4(uu[4], uu[5], uu[6], uu[7]);
    }
    reinterpret_cast<unsigned int*>(lds + 27648)[tid] = 0u;   // tap-27 zero plane
    __syncthreads();

    // ---------- B fragments -> registers ----------
    const int g  = lane >> 4;        // k-group
    const int g1 = g >> 1;           // tap parity within K=32 step
    const int ge = g & 1;            // ci half
    const int c0 = lane & 15;        // channel col / A row

    short8 bfr0[14], bfr1[14];
    {
        const char* bbase = lds + c0 * 32 + ge * 16 + g1 * 1024;
#pragma unroll
        for (int s = 0; s < 14; ++s) {
            bfr0[s] = *reinterpret_cast<const short8*>(bbase + s * 2048);
            bfr1[s] = *reinterpret_cast<const short8*>(bbase + s * 2048 + 512);
        }
    }
    __syncthreads();   // B reads done before slabs overwrite LDS

    const int c = cg * 4 + wid;
    if (c >= 961) return;            // after all syncthreads
    const int py = c / 31;
    const int px = c - py * 31;
    const int pz0 = rg * 8;
    const int npz = (rg == 3) ? 7 : 8;

    // per-lane constants
    const float inv0  = bg[c0]      * rsqrtf(bv[c0]      + 1e-5f);
    const float inv1  = bg[c0 + 16] * rsqrtf(bv[c0 + 16] + 1e-5f);
    const float bias0 = bb[c0]      - bm[c0]      * inv0;
    const float bias1 = bb[c0 + 16] - bm[c0 + 16] * inv1;
    const float4 wv0 = *reinterpret_cast<const float4*>(w2 + c0 * 4);
    const float4 wv1 = *reinterpret_cast<const float4*>(w2 + (c0 + 16) * 4);
    const int jj = lane & 31;
    const float w1v0 = w1[jj], w1v1 = w1[32 + jj], w1v2 = w1[64 + jj], w1v3 = w1[96 + jj];

    // ---------- phase 2: per-wave slab ----------
    char* slab = lds + wid * 10368;
    {   // zero whole slab (halo = per-patch conv zero padding)
        uint4 z = make_uint4(0u, 0u, 0u, 0u);
        uint4* sp = reinterpret_cast<uint4*>(slab);
        for (int i = lane; i < 648; i += 64) sp[i] = z;
    }

    const int fd = lane >> 4, fh = (lane >> 2) & 3, fw = lane & 3;
    char* sv = slab + ((fd + 1) * 36 + (fh + 1) * 6 + (fw + 1)) * 48;
    const char* abase = slab + ((c0 >> 2) * 6 + (c0 & 3)) * 48 + ge * 16;
    const float* xcol = x + (2 * py + fh) * 64 + (2 * px + fw);
    const bool loader = (fd >= 2);

    // initial fill for patch pz0 (all 64 lanes, 16 channels each)
    unsigned int u[8];
    {
        const float* xg = xcol + (2 * pz0 + fd) * 4096;
        float tv[16];
#pragma unroll
        for (int ci = 0; ci < 16; ++ci) tv[ci] = xg[ci * 262144];
#pragma unroll
        for (int j = 0; j < 8; ++j) u[j] = pack2(tv[2 * j], tv[2 * j + 1]);
    }
    *reinterpret_cast<uint4*>(sv)      = make_uint4(u[0], u[1], u[2], u[3]);
    *reinterpret_cast<uint4*>(sv + 16) = make_uint4(u[4], u[5], u[6], u[7]);
    asm volatile("s_waitcnt lgkmcnt(0)" ::: "memory");
    __builtin_amdgcn_sched_barrier(0);

    float carry[2][2] = {{0.f, 0.f}, {0.f, 0.f}};   // [jp][ch-half] for plane td=pz

    for (int it = 0; it < npz; ++it) {
        const int pz = pz0 + it;
        const bool pf = (it + 1 < npz);

        // prefetch next patch's two fresh d-planes (lanes fd>=2 only)
        float nv[16];
        if (pf && loader) {
            const float* xg2 = xcol + (2 * pz + 2 + fd) * 4096;
#pragma unroll
            for (int ci = 0; ci < 16; ++ci) nv[ci] = xg2[ci * 262144];
        }

        // ---- GEMM: M=64 pos x N=32 ch x K=448 ----
        f32x4 acc[4][2];
#pragma unroll
        for (int mm = 0; mm < 4; ++mm)
#pragma unroll
            for (int nn = 0; nn < 2; ++nn)
                acc[mm][nn] = (f32x4){0.f, 0.f, 0.f, 0.f};

#pragma unroll
        for (int s = 0; s < 14; ++s) {
            const int t0 = 2 * s, t1 = 2 * s + 1;
            const int D0 = ((t0 / 9) * 36 + ((t0 % 9) / 3) * 6 + (t0 % 3)) * 48;
            const int D1 = (t1 < 27) ? (((t1 / 9) * 36 + ((t1 % 9) / 3) * 6 + (t1 % 3)) * 48) : 0;
            const char* ap = abase + (g1 ? D1 : D0);
            short8 a0 = *reinterpret_cast<const short8*>(ap);
            short8 a1 = *reinterpret_cast<const short8*>(ap + 1728);
            short8 a2 = *reinterpret_cast<const short8*>(ap + 3456);
            short8 a3 = *reinterpret_cast<const short8*>(ap + 5184);
            acc[0][0] = __builtin_amdgcn_mfma_f32_16x16x32_bf16(a0, bfr0[s], acc[0][0], 0, 0, 0);
            acc[0][1] = __builtin_amdgcn_mfma_f32_16x16x32_bf16(a0, bfr1[s], acc[0][1], 0, 0, 0);
            acc[1][0] = __builtin_amdgcn_mfma_f32_16x16x32_bf16(a1, bfr0[s], acc[1][0], 0, 0, 0);
            acc[1][1] = __builtin_amdgcn_mfma_f32_16x16x32_bf16(a1, bfr1[s], acc[1][1], 0, 0, 0);
            acc[2][0] = __builtin_amdgcn_mfma_f32_16x16x32_bf16(a2, bfr0[s], acc[2][0], 0, 0, 0);
            acc[2][1] = __builtin_amdgcn_mfma_f32_16x16x32_bf16(a2, bfr1[s], acc[2][1], 0, 0, 0);
            acc[3][0] = __builtin_amdgcn_mfma_f32_16x16x32_bf16(a3, bfr0[s], acc[3][0], 0, 0, 0);
            acc[3][1] = __builtin_amdgcn_mfma_f32_16x16x32_bf16(a3, bfr1[s], acc[3][1], 0, 0, 0);
        }

        // ---- epilogue: bias+ReLU (C/D: col=lane&15, row=g*4+j; d=mm,h=g,w=j) ----
        float yv0[4][4], yv1[4][4];
#pragma unroll
        for (int mm = 0; mm < 4; ++mm)
#pragma unroll
            for (int j = 0; j < 4; ++j) {
                yv0[mm][j] = fmaxf(acc[mm][0][j] + bias0, 0.f);
                yv1[mm][j] = fmaxf(acc[mm][1][j] + bias1, 0.f);
            }

        // desc: mean over 64 positions per channel
        float p0 = 0.f, p1 = 0.f;
#pragma unroll
        for (int mm = 0; mm < 4; ++mm)
#pragma unroll
            for (int j = 0; j < 4; ++j) { p0 += yv0[mm][j]; p1 += yv1[mm][j]; }
        p0 += __shfl_xor(p0, 16); p0 += __shfl_xor(p0, 32);
        p1 += __shfl_xor(p1, 16); p1 += __shfl_xor(p1, 32);
        const float desc0 = p0 * (1.f / 64.f);
        const float desc1 = p1 * (1.f / 64.f);

        // SE (each 32-lane half holds the full 32-ch descriptor)
        const float dj = (lane & 16) ? desc1 : desc0;
        float z0 = dj * w1v0, z1 = dj * w1v1, z2 = dj * w1v2, z3 = dj * w1v3;
#pragma unroll
        for (int msk = 1; msk <= 16; msk <<= 1) {
            z0 += __shfl_xor(z0, msk);
            z1 += __shfl_xor(z1, msk);
            z2 += __shfl_xor(z2, msk);
            z3 += __shfl_xor(z3, msk);
        }
        z0 = fmaxf(z0, 0.f); z1 = fmaxf(z1, 0.f); z2 = fmaxf(z2, 0.f); z3 = fmaxf(z3, 0.f);
        const float s0 = z0 * wv0.x + z1 * wv0.y + z2 * wv0.z + z3 * wv0.w;
        const float s1 = z0 * wv1.x + z1 * wv1.y + z2 * wv1.z + z3 * wv1.w;
        const float attn0 = 0.125f / (1.f + __expf(-s0));   // 1/8 pool mean folded in
        const float attn1 = 0.125f / (1.f + __expf(-s1));

        // ---- 2x2x2 pool; mp=0 completes plane td=pz (with carry), mp=1 carried ----
        float pool0[2][2], pool1[2][2];   // [jp][ch-half]
#pragma unroll
        for (int mp = 0; mp < 2; ++mp)
#pragma unroll
            for (int jp = 0; jp < 2; ++jp) {
                float t0s = yv0[2 * mp][2 * jp] + yv0[2 * mp][2 * jp + 1] +
                            yv0[2 * mp + 1][2 * jp] + yv0[2 * mp + 1][2 * jp + 1];
                float t1s = yv1[2 * mp][2 * jp] + yv1[2 * mp][2 * jp + 1] +
                            yv1[2 * mp + 1][2 * jp] + yv1[2 * mp + 1][2 * jp + 1];
                t0s += __shfl_xor(t0s, 16);
                t1s += __shfl_xor(t1s, 16);
                if (mp == 0) { pool0[jp][0] = t0s * attn0; pool0[jp][1] = t1s * attn1; }
                else         { pool1[jp][0] = t0s * attn0; pool1[jp][1] = t1s * attn1; }
            }

        if ((g & 1) == 0) {               // writer lanes g in {0,2}
            const int th = py + (g >> 1);
            const int td = pz;
            const float cd  = (td == 0 || td == 31) ? 1.f : 2.f;
            const float chh = (th == 0 || th == 31) ? 1.f : 2.f;
#pragma unroll
            for (int jp = 0; jp < 2; ++jp) {
                const int tw = px + jp;
                const float cww = (tw == 0 || tw == 31) ? 1.f : 2.f;
                const float rw = 1.f / (cd * chh * cww);
                const int base = td * 1024 + th * 32 + tw;
                atomicAdd(out + c0 * 32768 + base,        (carry[jp][0] + pool0[jp][0]) * rw);
                atomicAdd(out + (c0 + 16) * 32768 + base, (carry[jp][1] + pool0[jp][1]) * rw);
            }
        }
        carry[0][0] = pool1[0][0]; carry[0][1] = pool1[0][1];
        carry[1][0] = pool1[1][0]; carry[1][1] = pool1[1][1];

        if (pf) {
            // shift shared d-planes: new fd {0,1} = old fd {2,3} (lane+32)
            unsigned int nu[8];
#pragma unroll
            for (int j = 0; j < 8; ++j) nu[j] = (unsigned int)__shfl((int)u[j], lane + 32);
            if (loader) {
#pragma unroll
                for (int j = 0; j < 8; ++j) u[j] = pack2(nv[2 * j], nv[2 * j + 1]);
            } else {
#pragma unroll
                for (int j = 0; j < 8; ++j) u[j] = nu[j];
            }
            asm volatile("s_waitcnt lgkmcnt(0)" ::: "memory");   // this iter's LDS reads retired
            __builtin_amdgcn_sched_barrier(0);
            *reinterpret_cast<uint4*>(sv)      = make_uint4(u[0], u[1], u[2], u[3]);
            *reinterpret_cast<uint4*>(sv + 16) = make_uint4(u[4], u[5], u[6], u[7]);
            asm volatile("s_waitcnt lgkmcnt(0)" ::: "memory");   // fill visible wave-wide
            __builtin_amdgcn_sched_barrier(0);
        }
    }

    // flush carried plane td = pz0 + npz
    if ((g & 1) == 0) {
        const int th = py + (g >> 1);
        const int td = pz0 + npz;
        const float cd  = (td == 0 || td == 31) ? 1.f : 2.f;
        const float chh = (th == 0 || th == 31) ? 1.f : 2.f;
#pragma unroll
        for (int jp = 0; jp < 2; ++jp) {
            const int tw = px + jp;
            const float cww = (tw == 0 || tw == 31) ? 1.f : 2.f;
            const float rw = 1.f / (cd * chh * cww);
            const int base = td * 1024 + th * 32 + tw;
            atomicAdd(out + c0 * 32768 + base,        carry[jp][0] * rw);
            atomicAdd(out + (c0 + 16) * 32768 + base, carry[jp][1] * rw);
        }
    }
}

// -------- residual: out = bn(conv1x1 stride-2)  (runs FIRST, pure write) --------
__global__ void res_kernel(const float* __restrict__ x,
                           const float* __restrict__ dw,
                           const float* __restrict__ dg,
                           const float* __restrict__ dbb,
                           const float* __restrict__ dm,
                           const float* __restrict__ dv,
                           float* __restrict__ out)
{
    const int t = blockIdx.x * 256 + threadIdx.x;     // 1,048,576 threads
    const int c = t >> 15;
    const int v = t & 32767;
    const int d = v >> 10, h = (v >> 5) & 31, w = v & 31;
    const float* xp = x + ((2 * d) * 4096 + (2 * h) * 64 + (2 * w));
    float acc = 0.f;
#pragma unroll
    for (int ci = 0; ci < 16; ++ci)
        acc = fmaf(xp[ci * 262144], dw[c * 16 + ci], acc);
    const float inv = dg[c] * rsqrtf(dv[c] + 1e-5f);
    out[t] = acc * inv + (dbb[c] - dm[c] * inv);
}

extern "C" void kernel_launch(void* const* d_in, const int* in_sizes, int n_in,
                              void* d_out, int out_size, void* d_ws, size_t ws_size,
                              hipStream_t stream)
{
    const float* x      = (const float*)d_in[0];
    const float* conv_w = (const float*)d_in[1];
    const float* bn_g   = (const float*)d_in[2];
    const float* bn_b   = (const float*)d_in[3];
    const float* bn_m   = (const float*)d_in[4];
    const float* bn_v   = (const float*)d_in[5];
    const float* se_w1  = (const float*)d_in[6];
    const float* se_w2  = (const float*)d_in[7];
    const float* down_w = (const float*)d_in[8];
    const float* dbn_g  = (const float*)d_in[9];
    const float* dbn_b  = (const float*)d_in[10];
    const float* dbn_m  = (const float*)d_in[11];
    const float* dbn_v  = (const float*)d_in[12];

    float* out = (float*)d_out;

    // residual initializes out (no memset, no read-modify-write)
    res_kernel<<<4096, 256, 0, stream>>>(x, down_w, dbn_g, dbn_b, dbn_m, dbn_v, out);

    // patch pipeline atomically accumulates on top
    patch_kernel<<<964, 256, 0, stream>>>(
        x, conv_w, bn_g, bn_b, bn_m, bn_v, se_w1, se_w2, out);
}

// Round 9
// 182.574 us; speedup vs baseline: 2.6565x; 1.7839x over previous
//
#include <hip/hip_runtime.h>
#include <hip/hip_bf16.h>

typedef short short8 __attribute__((ext_vector_type(8)));   // 8 bf16 raw bits
typedef float f32x4  __attribute__((ext_vector_type(4)));

#define PSF 953312            // plane stride in scratch: 29791 patches * 32 ch
#define SCR_FLOATS (8 * PSF)  // 7,626,496 floats = 30.5 MB

__device__ __forceinline__ unsigned short bfbits(float f) {
    __hip_bfloat16 h = __float2bfloat16(f);
    return *reinterpret_cast<unsigned short*>(&h);
}
__device__ __forceinline__ unsigned int pack2(float a, float b) {
    return (unsigned int)bfbits(a) | ((unsigned int)bfbits(b) << 16);
}

// ============================ patch kernel =============================
// MODE 0: atomicAdd into out (fallback).  MODE 1: plain stores into scr.
// Grid 964 = 241 column-groups x 4 pz-ranges. Block = 4 waves; wave w handles
// column c = cg*4+w (c = py*31+px), patches pz = rg*8 .. rg*8+npz-1.
template<int MODE>
__global__ __launch_bounds__(256, 2) void patch_kernel_t(
    const float* __restrict__ x,
    const float* __restrict__ cw,
    const float* __restrict__ bg,
    const float* __restrict__ bb,
    const float* __restrict__ bm,
    const float* __restrict__ bv,
    const float* __restrict__ w1,   // se_w1 [4][32]
    const float* __restrict__ w2,   // se_w2 [32][4]
    float* __restrict__ out,        // MODE 0
    float* __restrict__ scr)        // MODE 1
{
    __shared__ __align__(16) char lds[41472];

    const int tid  = threadIdx.x;
    const int wid  = tid >> 6;
    const int lane = tid & 63;

    // bijective XCD swizzle of 964 blocks (q=120, r=4)
    const int bi  = blockIdx.x;
    const int xcd = bi & 7, sidx = bi >> 3;
    const int wg  = (xcd < 4 ? xcd * 121 : 484 + (xcd - 4) * 120) + sidx;
    const int cg  = wg % 241;
    const int rg  = wg / 241;

    // ---------- phase 1: stage BN-folded bf16 weights into LDS ----------
    for (int p = tid; p < 864; p += 256) {          // 864 = 27*32 (tap,c)
        const int c   = p & 31;
        const int tap = p >> 5;
        const float inv = bg[c] * rsqrtf(bv[c] + 1e-5f);
        unsigned int uu[8];
#pragma unroll
        for (int j = 0; j < 8; ++j) {
            const float v0 = cw[c * 432 + (2 * j)     * 27 + tap] * inv;
            const float v1 = cw[c * 432 + (2 * j + 1) * 27 + tap] * inv;
            uu[j] = pack2(v0, v1);
        }
        uint4* dst = reinterpret_cast<uint4*>(lds + tap * 1024 + c * 32);
        dst[0] = make_uint4(uu[0], uu[1], uu[2], uu[3]);
        dst[1] = make_uint4(uu[4], uu[5], uu[6], uu[7]);
    }
    reinterpret_cast<unsigned int*>(lds + 27648)[tid] = 0u;   // tap-27 zero plane
    __syncthreads();

    // ---------- B fragments -> registers ----------
    const int g  = lane >> 4;        // k-group
    const int g1 = g >> 1;           // tap parity within K=32 step
    const int ge = g & 1;            // ci half
    const int c0 = lane & 15;        // channel col / A row

    short8 bfr0[14], bfr1[14];
    {
        const char* bbase = lds + c0 * 32 + ge * 16 + g1 * 1024;
#pragma unroll
        for (int s = 0; s < 14; ++s) {
            bfr0[s] = *reinterpret_cast<const short8*>(bbase + s * 2048);
            bfr1[s] = *reinterpret_cast<const short8*>(bbase + s * 2048 + 512);
        }
    }
    __syncthreads();   // B reads done before slabs overwrite LDS

    const int c = cg * 4 + wid;
    if (c >= 961) return;            // after all syncthreads
    const int py = c / 31;
    const int px = c - py * 31;
    const int pz0 = rg * 8;
    const int npz = (rg == 3) ? 7 : 8;

    // per-lane constants
    const float inv0  = bg[c0]      * rsqrtf(bv[c0]      + 1e-5f);
    const float inv1  = bg[c0 + 16] * rsqrtf(bv[c0 + 16] + 1e-5f);
    const float bias0 = bb[c0]      - bm[c0]      * inv0;
    const float bias1 = bb[c0 + 16] - bm[c0 + 16] * inv1;
    const float4 wv0 = *reinterpret_cast<const float4*>(w2 + c0 * 4);
    const float4 wv1 = *reinterpret_cast<const float4*>(w2 + (c0 + 16) * 4);
    const int jj = lane & 31;
    const float w1v0 = w1[jj], w1v1 = w1[32 + jj], w1v2 = w1[64 + jj], w1v3 = w1[96 + jj];

    // ---------- phase 2: per-wave slab ----------
    char* slab = lds + wid * 10368;
    {   // zero whole slab (halo = per-patch conv zero padding)
        uint4 z = make_uint4(0u, 0u, 0u, 0u);
        uint4* sp = reinterpret_cast<uint4*>(slab);
        for (int i = lane; i < 648; i += 64) sp[i] = z;
    }

    const int fd = lane >> 4, fh = (lane >> 2) & 3, fw = lane & 3;
    char* sv = slab + ((fd + 1) * 36 + (fh + 1) * 6 + (fw + 1)) * 48;
    const char* abase = slab + ((c0 >> 2) * 6 + (c0 & 3)) * 48 + ge * 16;
    const float* xcol = x + (2 * py + fh) * 64 + (2 * px + fw);
    const bool loader = (fd >= 2);

    // initial fill for patch pz0 (all 64 lanes, 16 channels each)
    unsigned int u[8];
    {
        const float* xg = xcol + (2 * pz0 + fd) * 4096;
        float tv[16];
#pragma unroll
        for (int ci = 0; ci < 16; ++ci) tv[ci] = xg[ci * 262144];
#pragma unroll
        for (int j = 0; j < 8; ++j) u[j] = pack2(tv[2 * j], tv[2 * j + 1]);
    }
    *reinterpret_cast<uint4*>(sv)      = make_uint4(u[0], u[1], u[2], u[3]);
    *reinterpret_cast<uint4*>(sv + 16) = make_uint4(u[4], u[5], u[6], u[7]);
    asm volatile("s_waitcnt lgkmcnt(0)" ::: "memory");
    __builtin_amdgcn_sched_barrier(0);

    float carry[2][2] = {{0.f, 0.f}, {0.f, 0.f}};   // [jp][ch-half] (MODE 0 only)

    for (int it = 0; it < npz; ++it) {
        const int pz = pz0 + it;
        const bool pf = (it + 1 < npz);

        // prefetch next patch's two fresh d-planes (lanes fd>=2 only)
        float nv[16];
        if (pf && loader) {
            const float* xg2 = xcol + (2 * pz + 2 + fd) * 4096;
#pragma unroll
            for (int ci = 0; ci < 16; ++ci) nv[ci] = xg2[ci * 262144];
        }

        // ---- GEMM: M=64 pos x N=32 ch x K=448 ----
        f32x4 acc[4][2];
#pragma unroll
        for (int mm = 0; mm < 4; ++mm)
#pragma unroll
            for (int nn = 0; nn < 2; ++nn)
                acc[mm][nn] = (f32x4){0.f, 0.f, 0.f, 0.f};

#pragma unroll
        for (int s = 0; s < 14; ++s) {
            const int t0 = 2 * s, t1 = 2 * s + 1;
            const int D0 = ((t0 / 9) * 36 + ((t0 % 9) / 3) * 6 + (t0 % 3)) * 48;
            const int D1 = (t1 < 27) ? (((t1 / 9) * 36 + ((t1 % 9) / 3) * 6 + (t1 % 3)) * 48) : 0;
            const char* ap = abase + (g1 ? D1 : D0);
            short8 a0 = *reinterpret_cast<const short8*>(ap);
            short8 a1 = *reinterpret_cast<const short8*>(ap + 1728);
            short8 a2 = *reinterpret_cast<const short8*>(ap + 3456);
            short8 a3 = *reinterpret_cast<const short8*>(ap + 5184);
            acc[0][0] = __builtin_amdgcn_mfma_f32_16x16x32_bf16(a0, bfr0[s], acc[0][0], 0, 0, 0);
            acc[0][1] = __builtin_amdgcn_mfma_f32_16x16x32_bf16(a0, bfr1[s], acc[0][1], 0, 0, 0);
            acc[1][0] = __builtin_amdgcn_mfma_f32_16x16x32_bf16(a1, bfr0[s], acc[1][0], 0, 0, 0);
            acc[1][1] = __builtin_amdgcn_mfma_f32_16x16x32_bf16(a1, bfr1[s], acc[1][1], 0, 0, 0);
            acc[2][0] = __builtin_amdgcn_mfma_f32_16x16x32_bf16(a2, bfr0[s], acc[2][0], 0, 0, 0);
            acc[2][1] = __builtin_amdgcn_mfma_f32_16x16x32_bf16(a2, bfr1[s], acc[2][1], 0, 0, 0);
            acc[3][0] = __builtin_amdgcn_mfma_f32_16x16x32_bf16(a3, bfr0[s], acc[3][0], 0, 0, 0);
            acc[3][1] = __builtin_amdgcn_mfma_f32_16x16x32_bf16(a3, bfr1[s], acc[3][1], 0, 0, 0);
        }

        // ---- epilogue: bias+ReLU (C/D: col=lane&15, row=g*4+j; d=mm,h=g,w=j) ----
        float yv0[4][4], yv1[4][4];
#pragma unroll
        for (int mm = 0; mm < 4; ++mm)
#pragma unroll
            for (int j = 0; j < 4; ++j) {
                yv0[mm][j] = fmaxf(acc[mm][0][j] + bias0, 0.f);
                yv1[mm][j] = fmaxf(acc[mm][1][j] + bias1, 0.f);
            }

        // desc: mean over 64 positions per channel
        float p0 = 0.f, p1 = 0.f;
#pragma unroll
        for (int mm = 0; mm < 4; ++mm)
#pragma unroll
            for (int j = 0; j < 4; ++j) { p0 += yv0[mm][j]; p1 += yv1[mm][j]; }
        p0 += __shfl_xor(p0, 16); p0 += __shfl_xor(p0, 32);
        p1 += __shfl_xor(p1, 16); p1 += __shfl_xor(p1, 32);
        const float desc0 = p0 * (1.f / 64.f);
        const float desc1 = p1 * (1.f / 64.f);

        // SE (each 32-lane half holds the full 32-ch descriptor)
        const float dj = (lane & 16) ? desc1 : desc0;
        float z0 = dj * w1v0, z1 = dj * w1v1, z2 = dj * w1v2, z3 = dj * w1v3;
#pragma unroll
        for (int msk = 1; msk <= 16; msk <<= 1) {
            z0 += __shfl_xor(z0, msk);
            z1 += __shfl_xor(z1, msk);
            z2 += __shfl_xor(z2, msk);
            z3 += __shfl_xor(z3, msk);
        }
        z0 = fmaxf(z0, 0.f); z1 = fmaxf(z1, 0.f); z2 = fmaxf(z2, 0.f); z3 = fmaxf(z3, 0.f);
        const float s0 = z0 * wv0.x + z1 * wv0.y + z2 * wv0.z + z3 * wv0.w;
        const float s1 = z0 * wv1.x + z1 * wv1.y + z2 * wv1.z + z3 * wv1.w;
        const float attn0 = 0.125f / (1.f + __expf(-s0));   // 1/8 pool mean folded in
        const float attn1 = 0.125f / (1.f + __expf(-s1));

        // ---- 2x2x2 pool: pool0 = local dz 0, pool1 = local dz 1 ----
        float pool0[2][2], pool1[2][2];   // [jp][ch-half]
#pragma unroll
        for (int mp = 0; mp < 2; ++mp)
#pragma unroll
            for (int jp = 0; jp < 2; ++jp) {
                float t0s = yv0[2 * mp][2 * jp] + yv0[2 * mp][2 * jp + 1] +
                            yv0[2 * mp + 1][2 * jp] + yv0[2 * mp + 1][2 * jp + 1];
                float t1s = yv1[2 * mp][2 * jp] + yv1[2 * mp][2 * jp + 1] +
                            yv1[2 * mp + 1][2 * jp] + yv1[2 * mp + 1][2 * jp + 1];
                t0s += __shfl_xor(t0s, 16);
                t1s += __shfl_xor(t1s, 16);
                if (mp == 0) { pool0[jp][0] = t0s * attn0; pool0[jp][1] = t1s * attn1; }
                else         { pool1[jp][0] = t0s * attn0; pool1[jp][1] = t1s * attn1; }
            }

        if ((g & 1) == 0) {               // writer lanes g in {0,2}; dh = g>>1
            const int dh = g >> 1;
            if (MODE == 1) {
                // plain scatter: scr[(dz*4 + dh*2 + jp)*PSF + pid*32 + ch]
                const int pid = pz * 961 + c;        // c = py*31+px
                float* sb = scr + pid * 32 + c0;
#pragma unroll
                for (int jp = 0; jp < 2; ++jp) {
                    sb[(dh * 2 + jp) * PSF]          = pool0[jp][0];
                    sb[(dh * 2 + jp) * PSF + 16]     = pool0[jp][1];
                    sb[(4 + dh * 2 + jp) * PSF]      = pool1[jp][0];
                    sb[(4 + dh * 2 + jp) * PSF + 16] = pool1[jp][1];
                }
            } else {
                const int th = py + dh;
                const int td = pz;
                const float cd  = (td == 0 || td == 31) ? 1.f : 2.f;
                const float chh = (th == 0 || th == 31) ? 1.f : 2.f;
#pragma unroll
                for (int jp = 0; jp < 2; ++jp) {
                    const int tw = px + jp;
                    const float cww = (tw == 0 || tw == 31) ? 1.f : 2.f;
                    const float rw = 1.f / (cd * chh * cww);
                    const int base = td * 1024 + th * 32 + tw;
                    atomicAdd(out + c0 * 32768 + base,        (carry[jp][0] + pool0[jp][0]) * rw);
                    atomicAdd(out + (c0 + 16) * 32768 + base, (carry[jp][1] + pool0[jp][1]) * rw);
                }
            }
        }
        if (MODE == 0) {
            carry[0][0] = pool1[0][0]; carry[0][1] = pool1[0][1];
            carry[1][0] = pool1[1][0]; carry[1][1] = pool1[1][1];
        }

        if (pf) {
            // shift shared d-planes: new fd {0,1} = old fd {2,3} (lane+32)
            unsigned int nu[8];
#pragma unroll
            for (int j = 0; j < 8; ++j) nu[j] = (unsigned int)__shfl((int)u[j], lane + 32);
            if (loader) {
#pragma unroll
                for (int j = 0; j < 8; ++j) u[j] = pack2(nv[2 * j], nv[2 * j + 1]);
            } else {
#pragma unroll
                for (int j = 0; j < 8; ++j) u[j] = nu[j];
            }
            asm volatile("s_waitcnt lgkmcnt(0)" ::: "memory");   // this iter's LDS reads retired
            __builtin_amdgcn_sched_barrier(0);
            *reinterpret_cast<uint4*>(sv)      = make_uint4(u[0], u[1], u[2], u[3]);
            *reinterpret_cast<uint4*>(sv + 16) = make_uint4(u[4], u[5], u[6], u[7]);
            asm volatile("s_waitcnt lgkmcnt(0)" ::: "memory");   // fill visible wave-wide
            __builtin_amdgcn_sched_barrier(0);
        }
    }

    // flush carried plane (MODE 0 only)
    if (MODE == 0 && (g & 1) == 0) {
        const int th = py + (g >> 1);
        const int td = pz0 + npz;
        const float cd  = (td == 0 || td == 31) ? 1.f : 2.f;
        const float chh = (th == 0 || th == 31) ? 1.f : 2.f;
#pragma unroll
        for (int jp = 0; jp < 2; ++jp) {
            const int tw = px + jp;
            const float cww = (tw == 0 || tw == 31) ? 1.f : 2.f;
            const float rw = 1.f / (cd * chh * cww);
            const int base = td * 1024 + th * 32 + tw;
            atomicAdd(out + c0 * 32768 + base,        carry[jp][0] * rw);
            atomicAdd(out + (c0 + 16) * 32768 + base, carry[jp][1] * rw);
        }
    }
}

// ============== phase 2: gather + coverage + fused residual ==============
// block <-> (td, th); thread t: c = t&31, group tg = t>>5 handles tw = tg*4..tg*4+3
__global__ __launch_bounds__(256) void gather_kernel(
    const float* __restrict__ scr,
    const float* __restrict__ x,
    const float* __restrict__ dwn,
    const float* __restrict__ dg,
    const float* __restrict__ dbb,
    const float* __restrict__ dm,
    const float* __restrict__ dv,
    float* __restrict__ out)
{
    __shared__ float tile[32][33];
    const int bd = blockIdx.x >> 5;    // td
    const int bh = blockIdx.x & 31;    // th
    const int t  = threadIdx.x;
    const int c  = t & 31;
    const int tg = t >> 5;

    const float inv  = dg[c] * rsqrtf(dv[c] + 1e-5f);
    const float bias = dbb[c] - dm[c] * inv;
    float dwr[16];
#pragma unroll
    for (int ci = 0; ci < 16; ++ci) dwr[ci] = dwn[c * 16 + ci] * inv;

    const float ndh = ((bd == 0 || bd == 31) ? 1.f : 2.f) *
                      ((bh == 0 || bh == 31) ? 1.f : 2.f);
    const float* xrow = x + (2 * bd) * 4096 + (2 * bh) * 64;

#pragma unroll
    for (int k = 0; k < 4; ++k) {
        const int tw = tg * 4 + k;
        float s = 0.f;
#pragma unroll
        for (int dz = 0; dz < 2; ++dz) {
            const int pz = bd - dz;
            if ((unsigned)pz > 30u) continue;
#pragma unroll
            for (int dh = 0; dh < 2; ++dh) {
                const int py = bh - dh;
                if ((unsigned)py > 30u) continue;
                const int rowb = (pz * 961 + py * 31) * 32 + c;
#pragma unroll
                for (int dw = 0; dw < 2; ++dw) {
                    const int px = tw - dw;
                    if ((unsigned)px > 30u) continue;
                    s += scr[((dz * 2 + dh) * 2 + dw) * PSF + rowb + px * 32];
                }
            }
        }
        const float nw = (tw == 0 || tw == 31) ? 1.f : 2.f;
        s *= 1.f / (ndh * nw);

        float r = 0.f;
        const float* xp = xrow + 2 * tw;
#pragma unroll
        for (int ci = 0; ci < 16; ++ci) r = fmaf(xp[ci * 262144], dwr[ci], r);
        tile[tw][c] = s + r + bias;
    }
    __syncthreads();

    // transposed coalesced write: lane tw-adjacent
    const int base = bd * 1024 + bh * 32;
    const int tw2 = t & 31;
#pragma unroll
    for (int k = 0; k < 4; ++k) {
        const int c2 = (t >> 5) * 4 + k;
        out[c2 * 32768 + base + tw2] = tile[tw2][c2];
    }
}

// -------- residual (fallback path only): out = bn(conv1x1 stride-2) --------
__global__ void res_kernel(const float* __restrict__ x,
                           const float* __restrict__ dw,
                           const float* __restrict__ dg,
                           const float* __restrict__ dbb,
                           const float* __restrict__ dm,
                           const float* __restrict__ dv,
                           float* __restrict__ out)
{
    const int t = blockIdx.x * 256 + threadIdx.x;
    const int c = t >> 15;
    const int v = t & 32767;
    const int d = v >> 10, h = (v >> 5) & 31, w = v & 31;
    const float* xp = x + ((2 * d) * 4096 + (2 * h) * 64 + (2 * w));
    float acc = 0.f;
#pragma unroll
    for (int ci = 0; ci < 16; ++ci)
        acc = fmaf(xp[ci * 262144], dw[c * 16 + ci], acc);
    const float inv = dg[c] * rsqrtf(dv[c] + 1e-5f);
    out[t] = acc * inv + (dbb[c] - dm[c] * inv);
}

extern "C" void kernel_launch(void* const* d_in, const int* in_sizes, int n_in,
                              void* d_out, int out_size, void* d_ws, size_t ws_size,
                              hipStream_t stream)
{
    (void)in_sizes; (void)n_in; (void)out_size;
    const float* x      = (const float*)d_in[0];
    const float* conv_w = (const float*)d_in[1];
    const float* bn_g   = (const float*)d_in[2];
    const float* bn_b   = (const float*)d_in[3];
    const float* bn_m   = (const float*)d_in[4];
    const float* bn_v   = (const float*)d_in[5];
    const float* se_w1  = (const float*)d_in[6];
    const float* se_w2  = (const float*)d_in[7];
    const float* down_w = (const float*)d_in[8];
    const float* dbn_g  = (const float*)d_in[9];
    const float* dbn_b  = (const float*)d_in[10];
    const float* dbn_m  = (const float*)d_in[11];
    const float* dbn_v  = (const float*)d_in[12];

    float* out = (float*)d_out;

    if (ws_size >= (size_t)SCR_FLOATS * 4) {
        // two-phase: scatter to scratch (no atomics), then gather + residual
        float* scr = (float*)d_ws;
        patch_kernel_t<1><<<964, 256, 0, stream>>>(
            x, conv_w, bn_g, bn_b, bn_m, bn_v, se_w1, se_w2, nullptr, scr);
        gather_kernel<<<1024, 256, 0, stream>>>(
            scr, x, down_w, dbn_g, dbn_b, dbn_m, dbn_v, out);
    } else {
        // fallback: proven atomic path
        res_kernel<<<4096, 256, 0, stream>>>(x, down_w, dbn_g, dbn_b, dbn_m, dbn_v, out);
        patch_kernel_t<0><<<964, 256, 0, stream>>>(
            x, conv_w, bn_g, bn_b, bn_m, bn_v, se_w1, se_w2, out, nullptr);
    }
}